// Round 12
// baseline (223.026 us; speedup 1.0000x reference)
//
#include <hip/hip_runtime.h>

typedef __bf16 bf16;
typedef __attribute__((ext_vector_type(8))) __bf16 bf16x8;
typedef __attribute__((ext_vector_type(4))) float f32x4;
typedef __attribute__((ext_vector_type(16))) float f32x16;
typedef unsigned int u32;

#define MFMA16(a, b, c) __builtin_amdgcn_mfma_f32_16x16x32_bf16((a), (b), (c), 0, 0, 0)
#define MFMA32(a, b, c) __builtin_amdgcn_mfma_f32_32x32x16_bf16((a), (b), (c), 0, 0, 0)

// Problem constants
#define BB 2
#define SS 2048
#define EE 1024
#define HH 16
#define DD 64
#define MM (BB * SS)  // 4096
#define NT (SS / 64)  // 32 K-tiles

__device__ inline f32x4 zero4() {
    f32x4 z; z.x = 0.f; z.y = 0.f; z.z = 0.f; z.w = 0.f; return z;
}

// async global->LDS DMA, 16B per lane.  LDS dest = wave-uniform base + lane*16.
__device__ __forceinline__ void gload16(const bf16* g, bf16* l) {
    __builtin_amdgcn_global_load_lds(
        (const __attribute__((address_space(1))) u32*)(const void*)g,
        (__attribute__((address_space(3))) u32*)(void*)l,
        16, 0, 0);
}

__device__ __forceinline__ u32 pkbf(float a, float b) {
    union { __bf16 h; unsigned short s; } ua, ub;
    ua.h = (__bf16)a; ub.h = (__bf16)b;
    return (u32)ua.s | ((u32)ub.s << 16);
}

// a' = {a.lo, b.lo}, b' = {a.hi, b.hi} — the exact redistribution softmax->PV
// needs (replaces 2 shfl + 6 selects per pair).  gfx950 instruction.
#define PSWAP(a, b) asm("v_permlane32_swap_b32 %0, %1" : "+v"(a), "+v"(b))

// ---------------------------------------------------------------------------
// Kernel 1: fused prep.  Grid 2818: [0,2048) query f32->bf16,
// [2048,2816) Wq/Wk/Wv transpose, [2816,2818) adapt.  (Wo transpose rides
// the attn dispatch tail — R11.)
// ---------------------------------------------------------------------------
__global__ __launch_bounds__(256) void prep_kernel(
    const float* __restrict__ query, bf16* __restrict__ qc,
    const float* __restrict__ s0, const float* __restrict__ s1,
    const float* __restrict__ s2,
    bf16* __restrict__ d0, bf16* __restrict__ d1,
    bf16* __restrict__ d2,
    const float* __restrict__ xi, const float* __restrict__ w1,
    const float* __restrict__ b1, const float* __restrict__ lng,
    const float* __restrict__ lnb, const float* __restrict__ w2,
    const float* __restrict__ b2, const float* __restrict__ gate,
    float* __restrict__ adapt) {
    __shared__ bf16 tile[64 * 72];
    const int bid = blockIdx.x;
    const int t = threadIdx.x;

    if (bid < 2048) {
        const int i = (bid * 256 + t) * 8;
        float4 a = *(const float4*)(query + i);
        float4 b = *(const float4*)(query + i + 4);
        bf16 tmp[8];
        tmp[0] = (bf16)a.x; tmp[1] = (bf16)a.y; tmp[2] = (bf16)a.z; tmp[3] = (bf16)a.w;
        tmp[4] = (bf16)b.x; tmp[5] = (bf16)b.y; tmp[6] = (bf16)b.z; tmp[7] = (bf16)b.w;
        *(uint4*)(qc + i) = *(uint4*)tmp;
    } else if (bid < 2816) {
        const int m = (bid - 2048) >> 8;
        const int idx0 = (bid - 2048) & 255;
        const float* W = (m == 0) ? s0 : (m == 1) ? s1 : s2;
        bf16* Wt = (m == 0) ? d0 : (m == 1) ? d1 : d2;
        const int k0 = (idx0 >> 4) * 64, n0 = (idx0 & 15) * 64;
#pragma unroll
        for (int i = 0; i < 2; ++i) {
            int idx = i * 256 + t;
            int r = idx >> 3, c = (idx & 7) * 8;
            float4 a = *(const float4*)(W + (k0 + r) * EE + n0 + c);
            float4 b = *(const float4*)(W + (k0 + r) * EE + n0 + c + 4);
            bf16 tmp[8];
            tmp[0] = (bf16)a.x; tmp[1] = (bf16)a.y; tmp[2] = (bf16)a.z; tmp[3] = (bf16)a.w;
            tmp[4] = (bf16)b.x; tmp[5] = (bf16)b.y; tmp[6] = (bf16)b.z; tmp[7] = (bf16)b.w;
            *(uint4*)(tile + r * 72 + c) = *(uint4*)tmp;
        }
        __syncthreads();
#pragma unroll
        for (int i = 0; i < 2; ++i) {
            int idx = i * 256 + t;
            int n = idx >> 3, kc = (idx & 7) * 8;
            bf16 tmp[8];
#pragma unroll
            for (int j = 0; j < 8; ++j) tmp[j] = tile[(kc + j) * 72 + n];
            *(uint4*)(Wt + (n0 + n) * EE + k0 + kc) = *(uint4*)tmp;
        }
    } else {
        const int b = bid - 2816;
        float* xs = (float*)tile;
        if (t < 64) {
            const float xiv = xi[b];
            float xv = 0.f;
            if (t < 32) xv = xiv * w1[t] + b1[t];
            float sm = xv;
            for (int off = 1; off < 32; off <<= 1) sm += __shfl_xor(sm, off);
            const float mu = sm * (1.f / 32.f);
            float dv = (t < 32) ? (xv - mu) : 0.f;
            float s2 = dv * dv;
            for (int off = 1; off < 32; off <<= 1) s2 += __shfl_xor(s2, off);
            const float var = s2 * (1.f / 32.f);
            if (t < 32) {
                float xn = (xv - mu) * rsqrtf(var + 1e-5f) * lng[t] + lnb[t];
                float ge = 0.5f * xn * (1.f + erff(xn * 0.70710678118654752f));
                xs[t] = ge;
            }
        }
        __syncthreads();
        if (t < 64) {
            float acc = b2[t];
            for (int j = 0; j < 32; ++j) acc += xs[j] * w2[j * DD + t];
            for (int h = 0; h < HH; ++h) {
                float sg = 1.f / (1.f + __expf(-gate[h]));
                adapt[(b * HH + h) * DD + t] = 1.f + sg * acc;
            }
        }
    }
}

// ---------------------------------------------------------------------------
// Kernel 2: QKV GEMM — 128x128 tile, BK=32, dbuf DMA, one barrier/iter.
// q-scale folds 0.125*log2(e) so attention uses bare v_exp_f32 (exp2).
// K and V^T outputs in PERMUTED TILE LAYOUT (R4):
//   idx = bh*131072 + kt*4096 + mf*2048 + c*512 + lane*8 + j
// Epilogue v2 (R5, verified): scaled results -> XOR-swizzled LDS tile ->
// 8 x dwordx4 stores/thread.  bias/adapt hoisted to per-column FMA factors.
// ---------------------------------------------------------------------------
__global__ __launch_bounds__(256, 3) void gemm_qkv(
    const bf16* __restrict__ Aq, const bf16* __restrict__ Bqk,
    const bf16* __restrict__ Av,
    const float* __restrict__ bias, const float* __restrict__ bias2,
    const float* __restrict__ bias3, const float* __restrict__ adapt,
    bf16* __restrict__ outqk, bf16* __restrict__ outvt) {
    __shared__ bf16 sh[16384];  // main loop: As/Bs; epilogue: 128x128 tile
    bf16* As = sh;
    bf16* Bs = sh + 8192;

    const int t = threadIdx.x;
    const int w = t >> 6, lane = t & 63;
    const int mrow = lane & 15, quad = lane >> 4;
    const int wm = (w & 1) * 64, wn = (w >> 1) * 64;

    int md, bx, by;
    const bf16 *Ap, *Bp;
    int bid = blockIdx.x;
    if (bid < 512) { md = 5; bx = bid & 31; by = bid >> 5; Ap = Aq; Bp = Bqk; }
    else { md = 4; bid -= 512; bx = bid & 7; by = bid >> 3; Ap = Av; Bp = Aq; }
    const int m0 = bx * 128, n0 = by * 128;
    const int m2 = (md == 5) ? (by >> 3) : 0;  // 0=Q, 1=K (block-uniform)

    f32x4 acc[4][4];
#pragma unroll
    for (int i = 0; i < 4; ++i)
#pragma unroll
        for (int j = 0; j < 4; ++j) acc[i][j] = zero4();

    const int dr = lane >> 2;
    const int dcg = ((lane & 3) ^ (dr & 3)) * 8;
    const bf16* Ag = Ap + (size_t)(m0 + w * 16 + dr) * EE + dcg;
    const bf16* Bg = Bp + (size_t)(n0 + w * 16 + dr) * EE + dcg;
    bf16* Al = As + (w * 16) * 32;
    bf16* Bl = Bs + (w * 16) * 32;

    gload16(Ag, Al);
    gload16(Ag + 64 * EE, Al + 64 * 32);
    gload16(Bg, Bl);
    gload16(Bg + 64 * EE, Bl + 64 * 32);

    for (int kt = 0; kt < 32; ++kt) {
        __syncthreads();
        if (kt < 31) {
            const int kn = (kt + 1) * 32;
            const int nb = (kt + 1) & 1;
            gload16(Ag + kn, Al + nb * 4096);
            gload16(Ag + 64 * EE + kn, Al + nb * 4096 + 64 * 32);
            gload16(Bg + kn, Bl + nb * 4096);
            gload16(Bg + 64 * EE + kn, Bl + nb * 4096 + 64 * 32);
        }
        const bf16* Ab = As + (kt & 1) * 4096;
        const bf16* Bb = Bs + (kt & 1) * 4096;
        const int sw = (quad ^ (mrow & 3)) * 8;
        bf16x8 af[4], bfr[4];
#pragma unroll
        for (int i = 0; i < 4; ++i)
            af[i] = *(const bf16x8*)(Ab + (wm + i * 16 + mrow) * 32 + sw);
#pragma unroll
        for (int j = 0; j < 4; ++j)
            bfr[j] = *(const bf16x8*)(Bb + (wn + j * 16 + mrow) * 32 + sw);
#pragma unroll
        for (int i = 0; i < 4; ++i)
#pragma unroll
            for (int j = 0; j < 4; ++j)
                acc[i][j] = MFMA16(af[i], bfr[j], acc[i][j]);
    }

    // ---- epilogue v2: scale -> swizzled LDS -> vectorized stores ----
    __syncthreads();  // staging LDS now dead; safe to overwrite

    if (md == 5) {
        const int bq_ = m0 >> 11;
        float cmul[4], cadd[4];
#pragma unroll
        for (int j = 0; j < 4; ++j) {
            const int cl = (n0 & 1023) + wn + j * 16 + mrow;
            const int hh = cl >> 6, dd2 = cl & 63;
            const float ad = adapt[(bq_ * HH + hh) * DD + dd2];
            const float sc = m2 ? 1.f : 0.18033688011113811f;
            cmul[j] = ad * sc;
            cadd[j] = (m2 ? bias2[cl] : bias[cl]) * ad * sc;
        }
#pragma unroll
        for (int i = 0; i < 4; ++i)
#pragma unroll
            for (int j = 0; j < 4; ++j) {
                const int lcol = wn + j * 16 + mrow;
#pragma unroll
                for (int r = 0; r < 4; ++r) {
                    const int lrow = wm + i * 16 + quad * 4 + r;
                    const float v = acc[i][j][r] * cmul[j] + cadd[j];
                    *(bf16*)((char*)sh + lrow * 256 +
                             ((lcol * 2) ^ ((lrow & 15) << 4))) = (bf16)v;
                }
            }
    } else {
        float radd[16];
#pragma unroll
        for (int i = 0; i < 4; ++i)
#pragma unroll
            for (int r = 0; r < 4; ++r)
                radd[i * 4 + r] = bias3[m0 + wm + i * 16 + quad * 4 + r];
#pragma unroll
        for (int i = 0; i < 4; ++i)
#pragma unroll
            for (int j = 0; j < 4; ++j) {
                const int lcol = wn + j * 16 + mrow;
#pragma unroll
                for (int r = 0; r < 4; ++r) {
                    const int lrow = wm + i * 16 + quad * 4 + r;
                    const float v = acc[i][j][r] + radd[i * 4 + r];
                    *(bf16*)((char*)sh + lrow * 256 +
                             ((lcol * 2) ^ ((lrow & 15) << 4))) = (bf16)v;
                }
            }
    }
    __syncthreads();

#pragma unroll
    for (int p = 0; p < 8; ++p) {
        const int lrow = p * 16 + (t >> 4);
        const int lcol0 = (t & 15) * 8;
        bf16x8 val = *(const bf16x8*)((const char*)sh + lrow * 256 +
                                      ((lcol0 * 2) ^ ((lrow & 15) << 4)));
        if (md == 5) {
            const int bq_ = m0 >> 11;
            const int s_ = (m0 + lrow) & (SS - 1);
            const int cl = (n0 & 1023) + lcol0;
            const int hh = cl >> 6, d0 = cl & 63;
            if (!m2) {
                *(bf16x8*)(outqk + ((size_t)(bq_ * HH + hh) * SS + s_) * DD + d0) = val;
            } else {
                const size_t base = (size_t)MM * EE + (size_t)(bq_ * HH + hh) * 131072;
                const int a2 = (s_ >> 6) * 4096 + ((s_ >> 5) & 1) * 2048 +
                               (d0 >> 4) * 512 +
                               ((s_ & 31) + ((d0 >> 3) & 1) * 32) * 8;
                *(bf16x8*)(outqk + base + a2) = val;
            }
        } else {
            const int rowv = m0 + lrow;
            const int hv = rowv >> 6, dv = rowv & 63;
            const int colv = n0 + lcol0;
            const int bv_ = colv >> 11, sv = colv & (SS - 1);
            const size_t base = (size_t)(bv_ * HH + hv) * 131072;
            const int a2 = (sv >> 6) * 4096 + (dv >> 5) * 2048 +
                           ((sv >> 4) & 3) * 512 +
                           ((dv & 31) + ((sv >> 3) & 1) * 32) * 8;
            *(bf16x8*)(outvt + base + a2) = val;
        }
    }
}

// ---------------------------------------------------------------------------
// Kernel 3: final GEMM (R5 epilogue v2, verified).
// ---------------------------------------------------------------------------
__global__ __launch_bounds__(256, 3) void gemm_o(
    const bf16* __restrict__ A, const bf16* __restrict__ Bt,
    const float* __restrict__ bias, float* __restrict__ outf) {
    __shared__ bf16 As[2 * 128 * 64];  // 32KB; epilogue reuses as 128x64 f32
    __shared__ bf16 Bs[2 * 64 * 64];

    const int t = threadIdx.x;
    const int w = t >> 6, lane = t & 63;
    const int mrow = lane & 15, quad = lane >> 4;
    const int m0 = blockIdx.x * 128, n0 = blockIdx.y * 64;

    f32x4 acc[2][4];
#pragma unroll
    for (int i = 0; i < 2; ++i)
#pragma unroll
        for (int j = 0; j < 4; ++j) acc[i][j] = zero4();

    const int grow = lane >> 3;
    const int gsw = ((lane & 7) ^ grow) * 8;
    const bf16* Ag = A + (size_t)(m0 + w * 32 + grow) * EE + gsw;
    const bf16* Bg = Bt + (size_t)(n0 + w * 16 + grow) * EE + gsw;
    bf16* Al = As + (w * 32) * 64;
    bf16* Bl = Bs + (w * 16) * 64;

#pragma unroll
    for (int i = 0; i < 4; ++i) gload16(Ag + i * 8 * EE, Al + i * 8 * 64);
#pragma unroll
    for (int i = 0; i < 2; ++i) gload16(Bg + i * 8 * EE, Bl + i * 8 * 64);

    for (int kt = 0; kt < 16; ++kt) {
        __syncthreads();
        if (kt < 15) {
            const int kn = (kt + 1) * 64;
            const int nb = (kt + 1) & 1;
#pragma unroll
            for (int i = 0; i < 4; ++i)
                gload16(Ag + i * 8 * EE + kn, Al + nb * 8192 + i * 8 * 64);
#pragma unroll
            for (int i = 0; i < 2; ++i)
                gload16(Bg + i * 8 * EE + kn, Bl + nb * 4096 + i * 8 * 64);
        }
        const bf16* Ab = As + (kt & 1) * 8192;
        const bf16* Bb = Bs + (kt & 1) * 4096;
#pragma unroll
        for (int ks = 0; ks < 2; ++ks) {
            const int cg = ks * 4 + quad;
            const int sw = (cg ^ (mrow & 7)) * 8;
            bf16x8 af[2], bfr[4];
#pragma unroll
            for (int mi = 0; mi < 2; ++mi)
                af[mi] = *(const bf16x8*)(Ab + (w * 32 + mi * 16 + mrow) * 64 + sw);
#pragma unroll
            for (int nj = 0; nj < 4; ++nj)
                bfr[nj] = *(const bf16x8*)(Bb + (nj * 16 + mrow) * 64 + sw);
#pragma unroll
            for (int mi = 0; mi < 2; ++mi)
#pragma unroll
                for (int nj = 0; nj < 4; ++nj)
                    acc[mi][nj] = MFMA16(af[mi], bfr[nj], acc[mi][nj]);
        }
    }

    // ---- epilogue v2 ----
    __syncthreads();  // staging LDS dead
    char* fs = (char*)As;  // 128 rows x 256B (64 f32), swizzled
    float cadd[4];
#pragma unroll
    for (int nj = 0; nj < 4; ++nj) cadd[nj] = bias[n0 + nj * 16 + mrow];
#pragma unroll
    for (int mi = 0; mi < 2; ++mi)
#pragma unroll
        for (int nj = 0; nj < 4; ++nj) {
            const int lcol = nj * 16 + mrow;
#pragma unroll
            for (int r = 0; r < 4; ++r) {
                const int lrow = w * 32 + mi * 16 + quad * 4 + r;
                *(float*)(fs + lrow * 256 + ((lcol * 4) ^ ((lrow & 15) << 4))) =
                    acc[mi][nj][r] + cadd[nj];
            }
        }
    __syncthreads();

#pragma unroll
    for (int p = 0; p < 8; ++p) {
        const int lrow = p * 16 + (t >> 4);
        const int lcol0 = (t & 15) * 4;
        float4 val = *(const float4*)(fs + lrow * 256 +
                                      ((lcol0 * 4) ^ ((lrow & 15) << 4)));
        *(float4*)(outf + (size_t)(m0 + lrow) * EE + n0 + lcol0) = val;
    }
}

// ---------------------------------------------------------------------------
// Kernel 4: flash attention — R12: lsum MOVED TO MFMA PIPE.
// R11 counters: VALUBusy 38 > MfmaUtil 26 — softmax VALU is the busier pipe.
// The row-sum Sigma_k p[k][q] is (ones)^T · P: computed with 4 extra
// MFMA32/tile using an all-ones A-fragment and the SAME post-PSWAP pb
// fragments PV uses.  Replaces 32 VALU adds/iter AND the final shfl (pb
// covers all 64 k/tile, so lacc[0] = complete row sum).  +16 VGPR (lacc),
// -ls[4]; ~140 VGPR, still grid-limited at 8 waves/CU.
// Normalization now uses the bf16-rounded p-hat actually fed to PV
// (self-consistent; absmax ~unchanged).
// Dead ends (final list): cross-block split-K (nondet), intra-block split-K
// (R9 spill / R10 -16%), K-tile 32/128, LDS K/V staging (R1-R3 lockstep),
// st-level by-ref pipeline (R6 spill), s_barrier clustering (R7 -8%),
// forced-occupancy launch bounds (R9/R12 spill), TLP raising (R10 null).
// ---------------------------------------------------------------------------
#define ATTN_SMPACK(ST0, ST1, PBN)                                           \
    do {                                                                     \
        u32 P32_[2][8];                                                      \
        _Pragma("unroll")                                                    \
        for (int rp = 0; rp < 8; ++rp) {                                     \
            float pa_ = __builtin_amdgcn_exp2f((ST0)[2 * rp]);               \
            float pb_ = __builtin_amdgcn_exp2f((ST0)[2 * rp + 1]);           \
            P32_[0][rp] = pkbf(pa_, pb_);                                    \
            float pc_ = __builtin_amdgcn_exp2f((ST1)[2 * rp]);               \
            float pd_ = __builtin_amdgcn_exp2f((ST1)[2 * rp + 1]);           \
            P32_[1][rp] = pkbf(pc_, pd_);                                    \
        }                                                                    \
        _Pragma("unroll")                                                    \
        for (int c = 0; c < 4; ++c) {                                        \
            const int mfs_ = c >> 1, ro_ = (c & 1) * 4;                      \
            u32 a0_ = P32_[mfs_][ro_ + 0], a1_ = P32_[mfs_][ro_ + 1];        \
            u32 b0_ = P32_[mfs_][ro_ + 2], b1_ = P32_[mfs_][ro_ + 3];        \
            PSWAP(a0_, b0_); PSWAP(a1_, b1_);                                \
            PBN[c * 4 + 0] = a0_; PBN[c * 4 + 1] = a1_;                      \
            PBN[c * 4 + 2] = b0_; PBN[c * 4 + 3] = b1_;                      \
            union { u32 u[4]; bf16x8 v; } pl_;                               \
            pl_.u[0] = a0_; pl_.u[1] = a1_; pl_.u[2] = b0_; pl_.u[3] = b1_;  \
            lacc = MFMA32(ones8, pl_.v, lacc);                               \
        }                                                                    \
    } while (0)

// tile T: load V(T)->VFN, cluster {QK(T) w/ KU, PV(T-1) w/ VFP,PBP},
// prefetch K(T+2)->KU, softmax(T)->PBN (+lacc row-sum MFMA).
#define ATTN_STEP(T, KU, VFP, VFN, PBP, PBN, DOPF)                           \
    do {                                                                     \
        _Pragma("unroll")                                                    \
        for (int mf = 0; mf < 2; ++mf)                                       \
            _Pragma("unroll")                                                \
            for (int c = 0; c < 4; ++c)                                      \
                VFN[mf * 4 + c] = *(const bf16x8*)(vbase + (T) * 4096 +      \
                                                   mf * 2048 + c * 512);     \
        f32x16 st0, st1;                                                     \
        _Pragma("unroll")                                                    \
        for (int i = 0; i < 16; ++i) { st0[i] = 0.f; st1[i] = 0.f; }         \
        __builtin_amdgcn_s_setprio(1);                                       \
        _Pragma("unroll")                                                    \
        for (int c = 0; c < 4; ++c) {                                        \
            st0 = MFMA32(KU[c], qf[c], st0);                                 \
            st1 = MFMA32(KU[4 + c], qf[c], st1);                             \
            union { u32 u[4]; bf16x8 v; } pv_;                               \
            pv_.u[0] = PBP[c * 4 + 0]; pv_.u[1] = PBP[c * 4 + 1];            \
            pv_.u[2] = PBP[c * 4 + 2]; pv_.u[3] = PBP[c * 4 + 3];            \
            oacc[0] = MFMA32(VFP[c], pv_.v, oacc[0]);                        \
            oacc[1] = MFMA32(VFP[4 + c], pv_.v, oacc[1]);                    \
        }                                                                    \
        __builtin_amdgcn_s_setprio(0);                                       \
        if (DOPF) {                                                          \
            const int ktp_ = ((T) + 2 < NT) ? (T) + 2 : NT - 1;              \
            _Pragma("unroll")                                                \
            for (int mf = 0; mf < 2; ++mf)                                   \
                _Pragma("unroll")                                            \
                for (int c = 0; c < 4; ++c)                                  \
                    KU[mf * 4 + c] = *(const bf16x8*)(kbase + ktp_ * 4096 +  \
                                                      mf * 2048 + c * 512);  \
        }                                                                    \
        ATTN_SMPACK(st0, st1, PBN);                                          \
    } while (0)

__global__ __launch_bounds__(256, 2) void attn_kernel(
    const bf16* __restrict__ q, const bf16* __restrict__ k,
    const bf16* __restrict__ vt, const float* __restrict__ wo,
    bf16* __restrict__ wot, bf16* __restrict__ o0) {
    __shared__ bf16 lds[4 * 2112];  // attn: epilogue transpose (wave-private)
                                    // tail blocks: 64x72 Wo transpose tile

    const int t = threadIdx.x;

    // ---- tail blocks (bid >= 512): Wo transpose (moved out of prep) ----
    if (blockIdx.x >= 512) {
        const int idx0 = blockIdx.x - 512;   // 0..255
        const int k0 = (idx0 >> 4) * 64, n0 = (idx0 & 15) * 64;
#pragma unroll
        for (int i = 0; i < 2; ++i) {
            int idx = i * 256 + t;
            int r = idx >> 3, c = (idx & 7) * 8;
            float4 a = *(const float4*)(wo + (k0 + r) * EE + n0 + c);
            float4 b = *(const float4*)(wo + (k0 + r) * EE + n0 + c + 4);
            bf16 tmp[8];
            tmp[0] = (bf16)a.x; tmp[1] = (bf16)a.y; tmp[2] = (bf16)a.z; tmp[3] = (bf16)a.w;
            tmp[4] = (bf16)b.x; tmp[5] = (bf16)b.y; tmp[6] = (bf16)b.z; tmp[7] = (bf16)b.w;
            *(uint4*)(lds + r * 72 + c) = *(uint4*)tmp;
        }
        __syncthreads();
#pragma unroll
        for (int i = 0; i < 2; ++i) {
            int idx = i * 256 + t;
            int n = idx >> 3, kc = (idx & 7) * 8;
            bf16 tmp[8];
#pragma unroll
            for (int j = 0; j < 8; ++j) tmp[j] = lds[(kc + j) * 72 + n];
            *(uint4*)(wot + (n0 + n) * EE + k0 + kc) = *(uint4*)tmp;
        }
        return;
    }

    const int w = t >> 6, lane = t & 63;
    const int q32 = lane & 31, h = lane >> 5;
    const int bh = blockIdx.x & 31;   // same-bh blocks share an XCD
    const int qb = blockIdx.x >> 5;   // 0..15 (128-row q tiles)
    const int qr0 = qb * 128 + w * 32;

    bf16x8 qf[4];
#pragma unroll
    for (int c = 0; c < 4; ++c)
        qf[c] = *(const bf16x8*)(q + (size_t)(bh * SS + qr0 + q32) * DD + c * 16 + h * 8);

    const bf16* kbase = k + (size_t)bh * 131072 + lane * 8;
    const bf16* vbase = vt + (size_t)bh * 131072 + lane * 8;

    // all-ones A-fragment for the lacc row-sum MFMA
    bf16x8 ones8;
#pragma unroll
    for (int j = 0; j < 8; ++j) ones8[j] = (bf16)1.f;

    f32x16 oacc[2], lacc;
#pragma unroll
    for (int i = 0; i < 16; ++i) { oacc[0][i] = 0.f; oacc[1][i] = 0.f; lacc[i] = 0.f; }

    bf16x8 Ka[8], Kb[8], vfA[8], vfB[8];
    u32 pbA[16], pbB[16];

    // prologue: K(0)->Ka, K(1)->Kb, V(0)->vfA
#pragma unroll
    for (int mf = 0; mf < 2; ++mf)
#pragma unroll
        for (int c = 0; c < 4; ++c) {
            Ka[mf * 4 + c] = *(const bf16x8*)(kbase + mf * 2048 + c * 512);
            Kb[mf * 4 + c] = *(const bf16x8*)(kbase + 4096 + mf * 2048 + c * 512);
            vfA[mf * 4 + c] = *(const bf16x8*)(vbase + mf * 2048 + c * 512);
        }

    // QK(0) -> softmax -> pbA; then K(2)->Ka (Ka dead after QK(0))
    {
        f32x16 st0, st1;
#pragma unroll
        for (int i = 0; i < 16; ++i) { st0[i] = 0.f; st1[i] = 0.f; }
        __builtin_amdgcn_s_setprio(1);
#pragma unroll
        for (int c = 0; c < 4; ++c) {
            st0 = MFMA32(Ka[c], qf[c], st0);
            st1 = MFMA32(Ka[4 + c], qf[c], st1);
        }
        __builtin_amdgcn_s_setprio(0);
#pragma unroll
        for (int mf = 0; mf < 2; ++mf)
#pragma unroll
            for (int c = 0; c < 4; ++c)
                Ka[mf * 4 + c] = *(const bf16x8*)(kbase + 2 * 4096 + mf * 2048 + c * 512);
        ATTN_SMPACK(st0, st1, pbA);
    }

    // pipeline: t = 1..30 (15 x 2 steps), then t = 31
    for (int i = 0; i < 15; ++i) {
        ATTN_STEP(2 * i + 1, Kb, vfA, vfB, pbA, pbB, 1);
        ATTN_STEP(2 * i + 2, Ka, vfB, vfA, pbB, pbA, 1);
    }
    ATTN_STEP(31, Kb, vfA, vfB, pbA, pbB, 0);

    // drain: PV(31) from vfB, pbB
    __builtin_amdgcn_s_setprio(1);
#pragma unroll
    for (int c = 0; c < 4; ++c) {
        union { u32 u[4]; bf16x8 v; } pv_;
        pv_.u[0] = pbB[c * 4 + 0]; pv_.u[1] = pbB[c * 4 + 1];
        pv_.u[2] = pbB[c * 4 + 2]; pv_.u[3] = pbB[c * 4 + 3];
        oacc[0] = MFMA32(vfB[c], pv_.v, oacc[0]);
        oacc[1] = MFMA32(vfB[4 + c], pv_.v, oacc[1]);
    }
    __builtin_amdgcn_s_setprio(0);

    // lacc rows are all equal = full row-sum for this lane's q-col
    // (post-PSWAP pb fragments cover all 64 k/tile; both lane halves hold
    // the same col = lane&31, so no cross-lane reduce is needed).
    const float inv = 1.f / lacc[0];

    bf16* ob = lds + w * 2112;  // 32 rows x stride 66, wave-private
#pragma unroll
    for (int mf = 0; mf < 2; ++mf)
#pragma unroll
        for (int rp = 0; rp < 8; ++rp) {
            const int d = 32 * mf + 2 * (rp & 1) + 8 * (rp >> 1) + 4 * h;
            *(u32*)(ob + q32 * 66 + d) =
                pkbf(oacc[mf][2 * rp] * inv, oacc[mf][2 * rp + 1] * inv);
        }
    __syncthreads();

    const int b = bh >> 4, head = bh & 15;
    const int half = lane & 1;
    const int r = lane >> 1;
#pragma unroll
    for (int i = 0; i < 4; ++i) {
        bf16x8 val = *(const bf16x8*)(ob + r * 66 + half * 32 + i * 8);
        *(bf16x8*)(o0 + (size_t)(b * SS + qr0 + r) * EE + head * DD +
                   half * 32 + i * 8) = val;
    }
}

// ---------------------------------------------------------------------------
// Single scratch layout, everything in d_ws (40 MiB).  d_out written exactly
// once, by gemm_o.
// ---------------------------------------------------------------------------
extern "C" void kernel_launch(void* const* d_in, const int* in_sizes, int n_in,
                              void* d_out, int out_size, void* d_ws, size_t ws_size,
                              hipStream_t stream) {
    const float* query = (const float*)d_in[0];
    const float* xi    = (const float*)d_in[1];
    const float* Wq = (const float*)d_in[2];  const float* bq = (const float*)d_in[3];
    const float* Wk = (const float*)d_in[4];  const float* bk = (const float*)d_in[5];
    const float* Wv = (const float*)d_in[6];  const float* bv = (const float*)d_in[7];
    const float* Wo = (const float*)d_in[8];  const float* bo = (const float*)d_in[9];
    const float* ew1 = (const float*)d_in[10]; const float* eb1 = (const float*)d_in[11];
    const float* lng = (const float*)d_in[12]; const float* lnb = (const float*)d_in[13];
    const float* ew2 = (const float*)d_in[14]; const float* eb2 = (const float*)d_in[15];
    const float* gate = (const float*)d_in[16];
    float* out = (float*)d_out;

    char* ws = (char*)d_ws;
    const size_t SZ = (size_t)MM * EE * sizeof(bf16);   // 8 MB
    const size_t WSZ = (size_t)EE * EE * sizeof(bf16);  // 2 MB per transposed weight

    bf16* queryc = (bf16*)(ws);            // dead after gemm_qkv
    bf16* p0     = (bf16*)(ws);            // attn output overlays queryc
    bf16* qws    = (bf16*)(ws + SZ);
    bf16* kws    = (bf16*)(ws + 2 * SZ);
    bf16* vtws   = (bf16*)(ws + 3 * SZ);
    bf16* wqT    = (bf16*)(ws + 4 * SZ);
    bf16* wkT    = (bf16*)(ws + 4 * SZ + WSZ);
    bf16* wvT    = (bf16*)(ws + 4 * SZ + 2 * WSZ);
    bf16* woT    = (bf16*)(ws + 4 * SZ + 3 * WSZ);
    float* adaptws = (float*)(ws + 4 * SZ + 4 * WSZ);

    // query conversion + Wq/Wk/Wv transpose + adapt (Wo transpose moved
    // to the attn dispatch tail)
    prep_kernel<<<2818, 256, 0, stream>>>(query, queryc, Wq, Wk, Wv,
                                          wqT, wkT, wvT,
                                          xi, ew1, eb1, lng, lnb, ew2, eb2, gate,
                                          adaptws);

    // combined QK (512) + V^T (256) = 768 blocks = 3/CU
    gemm_qkv<<<768, 256, 0, stream>>>(queryc, wqT, wvT, bq, bk, bv, adaptws,
                                      qws, vtws);

    // 512 attn blocks (32 bh x 16 q-tiles) + 256 Wo-transpose tail blocks
    attn_kernel<<<768, 256, 0, stream>>>(qws, kws, vtws, Wo, woT, p0);

    gemm_o<<<dim3(MM / 128, EE / 64), 256, 0, stream>>>(p0, woT, bo, out);
}

// Round 13
// 203.874 us; speedup vs baseline: 1.0939x; 1.0939x over previous
//
#include <hip/hip_runtime.h>

typedef __bf16 bf16;
typedef __attribute__((ext_vector_type(8))) __bf16 bf16x8;
typedef __attribute__((ext_vector_type(4))) float f32x4;
typedef __attribute__((ext_vector_type(16))) float f32x16;
typedef unsigned int u32;

#define MFMA16(a, b, c) __builtin_amdgcn_mfma_f32_16x16x32_bf16((a), (b), (c), 0, 0, 0)
#define MFMA32(a, b, c) __builtin_amdgcn_mfma_f32_32x32x16_bf16((a), (b), (c), 0, 0, 0)

// Problem constants
#define BB 2
#define SS 2048
#define EE 1024
#define HH 16
#define DD 64
#define MM (BB * SS)  // 4096
#define NT (SS / 64)  // 32 K-tiles

__device__ inline f32x4 zero4() {
    f32x4 z; z.x = 0.f; z.y = 0.f; z.z = 0.f; z.w = 0.f; return z;
}

// async global->LDS DMA, 16B per lane.  LDS dest = wave-uniform base + lane*16.
__device__ __forceinline__ void gload16(const bf16* g, bf16* l) {
    __builtin_amdgcn_global_load_lds(
        (const __attribute__((address_space(1))) u32*)(const void*)g,
        (__attribute__((address_space(3))) u32*)(void*)l,
        16, 0, 0);
}

__device__ __forceinline__ u32 pkbf(float a, float b) {
    union { __bf16 h; unsigned short s; } ua, ub;
    ua.h = (__bf16)a; ub.h = (__bf16)b;
    return (u32)ua.s | ((u32)ub.s << 16);
}

// a' = {a.lo, b.lo}, b' = {a.hi, b.hi} — the exact redistribution softmax->PV
// needs (replaces 2 shfl + 6 selects per pair).  gfx950 instruction.
#define PSWAP(a, b) asm("v_permlane32_swap_b32 %0, %1" : "+v"(a), "+v"(b))

// ---------------------------------------------------------------------------
// Kernel 1: fused prep.  Grid 2818: [0,2048) query f32->bf16,
// [2048,2816) Wq/Wk/Wv transpose, [2816,2818) adapt.  (Wo transpose rides
// the attn dispatch tail — R11.)
// ---------------------------------------------------------------------------
__global__ __launch_bounds__(256) void prep_kernel(
    const float* __restrict__ query, bf16* __restrict__ qc,
    const float* __restrict__ s0, const float* __restrict__ s1,
    const float* __restrict__ s2,
    bf16* __restrict__ d0, bf16* __restrict__ d1,
    bf16* __restrict__ d2,
    const float* __restrict__ xi, const float* __restrict__ w1,
    const float* __restrict__ b1, const float* __restrict__ lng,
    const float* __restrict__ lnb, const float* __restrict__ w2,
    const float* __restrict__ b2, const float* __restrict__ gate,
    float* __restrict__ adapt) {
    __shared__ bf16 tile[64 * 72];
    const int bid = blockIdx.x;
    const int t = threadIdx.x;

    if (bid < 2048) {
        const int i = (bid * 256 + t) * 8;
        float4 a = *(const float4*)(query + i);
        float4 b = *(const float4*)(query + i + 4);
        bf16 tmp[8];
        tmp[0] = (bf16)a.x; tmp[1] = (bf16)a.y; tmp[2] = (bf16)a.z; tmp[3] = (bf16)a.w;
        tmp[4] = (bf16)b.x; tmp[5] = (bf16)b.y; tmp[6] = (bf16)b.z; tmp[7] = (bf16)b.w;
        *(uint4*)(qc + i) = *(uint4*)tmp;
    } else if (bid < 2816) {
        const int m = (bid - 2048) >> 8;
        const int idx0 = (bid - 2048) & 255;
        const float* W = (m == 0) ? s0 : (m == 1) ? s1 : s2;
        bf16* Wt = (m == 0) ? d0 : (m == 1) ? d1 : d2;
        const int k0 = (idx0 >> 4) * 64, n0 = (idx0 & 15) * 64;
#pragma unroll
        for (int i = 0; i < 2; ++i) {
            int idx = i * 256 + t;
            int r = idx >> 3, c = (idx & 7) * 8;
            float4 a = *(const float4*)(W + (k0 + r) * EE + n0 + c);
            float4 b = *(const float4*)(W + (k0 + r) * EE + n0 + c + 4);
            bf16 tmp[8];
            tmp[0] = (bf16)a.x; tmp[1] = (bf16)a.y; tmp[2] = (bf16)a.z; tmp[3] = (bf16)a.w;
            tmp[4] = (bf16)b.x; tmp[5] = (bf16)b.y; tmp[6] = (bf16)b.z; tmp[7] = (bf16)b.w;
            *(uint4*)(tile + r * 72 + c) = *(uint4*)tmp;
        }
        __syncthreads();
#pragma unroll
        for (int i = 0; i < 2; ++i) {
            int idx = i * 256 + t;
            int n = idx >> 3, kc = (idx & 7) * 8;
            bf16 tmp[8];
#pragma unroll
            for (int j = 0; j < 8; ++j) tmp[j] = tile[(kc + j) * 72 + n];
            *(uint4*)(Wt + (n0 + n) * EE + k0 + kc) = *(uint4*)tmp;
        }
    } else {
        const int b = bid - 2816;
        float* xs = (float*)tile;
        if (t < 64) {
            const float xiv = xi[b];
            float xv = 0.f;
            if (t < 32) xv = xiv * w1[t] + b1[t];
            float sm = xv;
            for (int off = 1; off < 32; off <<= 1) sm += __shfl_xor(sm, off);
            const float mu = sm * (1.f / 32.f);
            float dv = (t < 32) ? (xv - mu) : 0.f;
            float s2 = dv * dv;
            for (int off = 1; off < 32; off <<= 1) s2 += __shfl_xor(s2, off);
            const float var = s2 * (1.f / 32.f);
            if (t < 32) {
                float xn = (xv - mu) * rsqrtf(var + 1e-5f) * lng[t] + lnb[t];
                float ge = 0.5f * xn * (1.f + erff(xn * 0.70710678118654752f));
                xs[t] = ge;
            }
        }
        __syncthreads();
        if (t < 64) {
            float acc = b2[t];
            for (int j = 0; j < 32; ++j) acc += xs[j] * w2[j * DD + t];
            for (int h = 0; h < HH; ++h) {
                float sg = 1.f / (1.f + __expf(-gate[h]));
                adapt[(b * HH + h) * DD + t] = 1.f + sg * acc;
            }
        }
    }
}

// ---------------------------------------------------------------------------
// Kernel 2: QKV GEMM — 128x128 tile, BK=32, dbuf DMA, one barrier/iter.
// q-scale folds 0.125*log2(e) so attention uses bare v_exp_f32 (exp2).
// K and V^T outputs in PERMUTED TILE LAYOUT (R4):
//   idx = bh*131072 + kt*4096 + mf*2048 + c*512 + lane*8 + j
// Epilogue v2 (R5, verified): scaled results -> XOR-swizzled LDS tile ->
// 8 x dwordx4 stores/thread.  bias/adapt hoisted to per-column FMA factors.
// ---------------------------------------------------------------------------
__global__ __launch_bounds__(256, 3) void gemm_qkv(
    const bf16* __restrict__ Aq, const bf16* __restrict__ Bqk,
    const bf16* __restrict__ Av,
    const float* __restrict__ bias, const float* __restrict__ bias2,
    const float* __restrict__ bias3, const float* __restrict__ adapt,
    bf16* __restrict__ outqk, bf16* __restrict__ outvt) {
    __shared__ bf16 sh[16384];  // main loop: As/Bs; epilogue: 128x128 tile
    bf16* As = sh;
    bf16* Bs = sh + 8192;

    const int t = threadIdx.x;
    const int w = t >> 6, lane = t & 63;
    const int mrow = lane & 15, quad = lane >> 4;
    const int wm = (w & 1) * 64, wn = (w >> 1) * 64;

    int md, bx, by;
    const bf16 *Ap, *Bp;
    int bid = blockIdx.x;
    if (bid < 512) { md = 5; bx = bid & 31; by = bid >> 5; Ap = Aq; Bp = Bqk; }
    else { md = 4; bid -= 512; bx = bid & 7; by = bid >> 3; Ap = Av; Bp = Aq; }
    const int m0 = bx * 128, n0 = by * 128;
    const int m2 = (md == 5) ? (by >> 3) : 0;  // 0=Q, 1=K (block-uniform)

    f32x4 acc[4][4];
#pragma unroll
    for (int i = 0; i < 4; ++i)
#pragma unroll
        for (int j = 0; j < 4; ++j) acc[i][j] = zero4();

    const int dr = lane >> 2;
    const int dcg = ((lane & 3) ^ (dr & 3)) * 8;
    const bf16* Ag = Ap + (size_t)(m0 + w * 16 + dr) * EE + dcg;
    const bf16* Bg = Bp + (size_t)(n0 + w * 16 + dr) * EE + dcg;
    bf16* Al = As + (w * 16) * 32;
    bf16* Bl = Bs + (w * 16) * 32;

    gload16(Ag, Al);
    gload16(Ag + 64 * EE, Al + 64 * 32);
    gload16(Bg, Bl);
    gload16(Bg + 64 * EE, Bl + 64 * 32);

    for (int kt = 0; kt < 32; ++kt) {
        __syncthreads();
        if (kt < 31) {
            const int kn = (kt + 1) * 32;
            const int nb = (kt + 1) & 1;
            gload16(Ag + kn, Al + nb * 4096);
            gload16(Ag + 64 * EE + kn, Al + nb * 4096 + 64 * 32);
            gload16(Bg + kn, Bl + nb * 4096);
            gload16(Bg + 64 * EE + kn, Bl + nb * 4096 + 64 * 32);
        }
        const bf16* Ab = As + (kt & 1) * 4096;
        const bf16* Bb = Bs + (kt & 1) * 4096;
        const int sw = (quad ^ (mrow & 3)) * 8;
        bf16x8 af[4], bfr[4];
#pragma unroll
        for (int i = 0; i < 4; ++i)
            af[i] = *(const bf16x8*)(Ab + (wm + i * 16 + mrow) * 32 + sw);
#pragma unroll
        for (int j = 0; j < 4; ++j)
            bfr[j] = *(const bf16x8*)(Bb + (wn + j * 16 + mrow) * 32 + sw);
#pragma unroll
        for (int i = 0; i < 4; ++i)
#pragma unroll
            for (int j = 0; j < 4; ++j)
                acc[i][j] = MFMA16(af[i], bfr[j], acc[i][j]);
    }

    // ---- epilogue v2: scale -> swizzled LDS -> vectorized stores ----
    __syncthreads();  // staging LDS now dead; safe to overwrite

    if (md == 5) {
        const int bq_ = m0 >> 11;
        float cmul[4], cadd[4];
#pragma unroll
        for (int j = 0; j < 4; ++j) {
            const int cl = (n0 & 1023) + wn + j * 16 + mrow;
            const int hh = cl >> 6, dd2 = cl & 63;
            const float ad = adapt[(bq_ * HH + hh) * DD + dd2];
            const float sc = m2 ? 1.f : 0.18033688011113811f;
            cmul[j] = ad * sc;
            cadd[j] = (m2 ? bias2[cl] : bias[cl]) * ad * sc;
        }
#pragma unroll
        for (int i = 0; i < 4; ++i)
#pragma unroll
            for (int j = 0; j < 4; ++j) {
                const int lcol = wn + j * 16 + mrow;
#pragma unroll
                for (int r = 0; r < 4; ++r) {
                    const int lrow = wm + i * 16 + quad * 4 + r;
                    const float v = acc[i][j][r] * cmul[j] + cadd[j];
                    *(bf16*)((char*)sh + lrow * 256 +
                             ((lcol * 2) ^ ((lrow & 15) << 4))) = (bf16)v;
                }
            }
    } else {
        float radd[16];
#pragma unroll
        for (int i = 0; i < 4; ++i)
#pragma unroll
            for (int r = 0; r < 4; ++r)
                radd[i * 4 + r] = bias3[m0 + wm + i * 16 + quad * 4 + r];
#pragma unroll
        for (int i = 0; i < 4; ++i)
#pragma unroll
            for (int j = 0; j < 4; ++j) {
                const int lcol = wn + j * 16 + mrow;
#pragma unroll
                for (int r = 0; r < 4; ++r) {
                    const int lrow = wm + i * 16 + quad * 4 + r;
                    const float v = acc[i][j][r] + radd[i * 4 + r];
                    *(bf16*)((char*)sh + lrow * 256 +
                             ((lcol * 2) ^ ((lrow & 15) << 4))) = (bf16)v;
                }
            }
    }
    __syncthreads();

#pragma unroll
    for (int p = 0; p < 8; ++p) {
        const int lrow = p * 16 + (t >> 4);
        const int lcol0 = (t & 15) * 8;
        bf16x8 val = *(const bf16x8*)((const char*)sh + lrow * 256 +
                                      ((lcol0 * 2) ^ ((lrow & 15) << 4)));
        if (md == 5) {
            const int bq_ = m0 >> 11;
            const int s_ = (m0 + lrow) & (SS - 1);
            const int cl = (n0 & 1023) + lcol0;
            const int hh = cl >> 6, d0 = cl & 63;
            if (!m2) {
                *(bf16x8*)(outqk + ((size_t)(bq_ * HH + hh) * SS + s_) * DD + d0) = val;
            } else {
                const size_t base = (size_t)MM * EE + (size_t)(bq_ * HH + hh) * 131072;
                const int a2 = (s_ >> 6) * 4096 + ((s_ >> 5) & 1) * 2048 +
                               (d0 >> 4) * 512 +
                               ((s_ & 31) + ((d0 >> 3) & 1) * 32) * 8;
                *(bf16x8*)(outqk + base + a2) = val;
            }
        } else {
            const int rowv = m0 + lrow;
            const int hv = rowv >> 6, dv = rowv & 63;
            const int colv = n0 + lcol0;
            const int bv_ = colv >> 11, sv = colv & (SS - 1);
            const size_t base = (size_t)(bv_ * HH + hv) * 131072;
            const int a2 = (sv >> 6) * 4096 + (dv >> 5) * 2048 +
                           ((sv >> 4) & 3) * 512 +
                           ((dv & 31) + ((sv >> 3) & 1) * 32) * 8;
            *(bf16x8*)(outvt + base + a2) = val;
        }
    }
}

// ---------------------------------------------------------------------------
// Kernel 3: final GEMM (R5 epilogue v2, verified).
// ---------------------------------------------------------------------------
__global__ __launch_bounds__(256, 3) void gemm_o(
    const bf16* __restrict__ A, const bf16* __restrict__ Bt,
    const float* __restrict__ bias, float* __restrict__ outf) {
    __shared__ bf16 As[2 * 128 * 64];  // 32KB; epilogue reuses as 128x64 f32
    __shared__ bf16 Bs[2 * 64 * 64];

    const int t = threadIdx.x;
    const int w = t >> 6, lane = t & 63;
    const int mrow = lane & 15, quad = lane >> 4;
    const int m0 = blockIdx.x * 128, n0 = blockIdx.y * 64;

    f32x4 acc[2][4];
#pragma unroll
    for (int i = 0; i < 2; ++i)
#pragma unroll
        for (int j = 0; j < 4; ++j) acc[i][j] = zero4();

    const int grow = lane >> 3;
    const int gsw = ((lane & 7) ^ grow) * 8;
    const bf16* Ag = A + (size_t)(m0 + w * 32 + grow) * EE + gsw;
    const bf16* Bg = Bt + (size_t)(n0 + w * 16 + grow) * EE + gsw;
    bf16* Al = As + (w * 32) * 64;
    bf16* Bl = Bs + (w * 16) * 64;

#pragma unroll
    for (int i = 0; i < 4; ++i) gload16(Ag + i * 8 * EE, Al + i * 8 * 64);
#pragma unroll
    for (int i = 0; i < 2; ++i) gload16(Bg + i * 8 * EE, Bl + i * 8 * 64);

    for (int kt = 0; kt < 16; ++kt) {
        __syncthreads();
        if (kt < 15) {
            const int kn = (kt + 1) * 64;
            const int nb = (kt + 1) & 1;
#pragma unroll
            for (int i = 0; i < 4; ++i)
                gload16(Ag + i * 8 * EE + kn, Al + nb * 8192 + i * 8 * 64);
#pragma unroll
            for (int i = 0; i < 2; ++i)
                gload16(Bg + i * 8 * EE + kn, Bl + nb * 4096 + i * 8 * 64);
        }
        const bf16* Ab = As + (kt & 1) * 8192;
        const bf16* Bb = Bs + (kt & 1) * 4096;
#pragma unroll
        for (int ks = 0; ks < 2; ++ks) {
            const int cg = ks * 4 + quad;
            const int sw = (cg ^ (mrow & 7)) * 8;
            bf16x8 af[2], bfr[4];
#pragma unroll
            for (int mi = 0; mi < 2; ++mi)
                af[mi] = *(const bf16x8*)(Ab + (w * 32 + mi * 16 + mrow) * 64 + sw);
#pragma unroll
            for (int nj = 0; nj < 4; ++nj)
                bfr[nj] = *(const bf16x8*)(Bb + (nj * 16 + mrow) * 64 + sw);
#pragma unroll
            for (int mi = 0; mi < 2; ++mi)
#pragma unroll
                for (int nj = 0; nj < 4; ++nj)
                    acc[mi][nj] = MFMA16(af[mi], bfr[nj], acc[mi][nj]);
        }
    }

    // ---- epilogue v2 ----
    __syncthreads();  // staging LDS dead
    char* fs = (char*)As;  // 128 rows x 256B (64 f32), swizzled
    float cadd[4];
#pragma unroll
    for (int nj = 0; nj < 4; ++nj) cadd[nj] = bias[n0 + nj * 16 + mrow];
#pragma unroll
    for (int mi = 0; mi < 2; ++mi)
#pragma unroll
        for (int nj = 0; nj < 4; ++nj) {
            const int lcol = nj * 16 + mrow;
#pragma unroll
            for (int r = 0; r < 4; ++r) {
                const int lrow = w * 32 + mi * 16 + quad * 4 + r;
                *(float*)(fs + lrow * 256 + ((lcol * 4) ^ ((lrow & 15) << 4))) =
                    acc[mi][nj][r] + cadd[nj];
            }
        }
    __syncthreads();

#pragma unroll
    for (int p = 0; p < 8; ++p) {
        const int lrow = p * 16 + (t >> 4);
        const int lcol0 = (t & 15) * 4;
        float4 val = *(const float4*)(fs + lrow * 256 +
                                      ((lcol0 * 4) ^ ((lrow & 15) << 4)));
        *(float4*)(outf + (size_t)(m0 + lrow) * EE + n0 + lcol0) = val;
    }
}

// ---------------------------------------------------------------------------
// Kernel 4: flash attention — R13: PURE REVERT to R11 (measured best:
// total 205.3us, attn 54.5us).  R12's lsum-via-MFMA regressed (VGPR spill at
// the 128 boundary + 25% more MFMA on the critical chain) — reverted.
// Structure: R8 P32-level pipeline + permlane redistribution; Wo-transpose
// tail blocks (bid>=512) overlap pure-memory work under attn's idle BW.
// Dead ends (final): cross-block split-K (nondet), intra-block split-K
// (R9 spill / R10 -16%), K-tile 32/128, LDS K/V staging (R1-R3 lockstep),
// st-level by-ref pipeline (R6 spill), s_barrier clustering (R7 -8%),
// forced-occupancy bounds (R9 spill), TLP raising (R10 null),
// lsum-via-MFMA (R12 spill+chain).  Attn plateau ~52-54us in this
// decomposition; all in-structure levers measured.
// ---------------------------------------------------------------------------
#define ATTN_SMPACK(ST0, ST1, PBN)                                           \
    do {                                                                     \
        u32 P32_[2][8];                                                      \
        _Pragma("unroll")                                                    \
        for (int rp = 0; rp < 8; ++rp) {                                     \
            float pa_ = __builtin_amdgcn_exp2f((ST0)[2 * rp]);               \
            float pb_ = __builtin_amdgcn_exp2f((ST0)[2 * rp + 1]);           \
            ls[rp & 3] += pa_ + pb_;                                         \
            P32_[0][rp] = pkbf(pa_, pb_);                                    \
            float pc_ = __builtin_amdgcn_exp2f((ST1)[2 * rp]);               \
            float pd_ = __builtin_amdgcn_exp2f((ST1)[2 * rp + 1]);           \
            ls[rp & 3] += pc_ + pd_;                                         \
            P32_[1][rp] = pkbf(pc_, pd_);                                    \
        }                                                                    \
        _Pragma("unroll")                                                    \
        for (int c = 0; c < 4; ++c) {                                        \
            const int mfs_ = c >> 1, ro_ = (c & 1) * 4;                      \
            u32 a0_ = P32_[mfs_][ro_ + 0], a1_ = P32_[mfs_][ro_ + 1];        \
            u32 b0_ = P32_[mfs_][ro_ + 2], b1_ = P32_[mfs_][ro_ + 3];        \
            PSWAP(a0_, b0_); PSWAP(a1_, b1_);                                \
            PBN[c * 4 + 0] = a0_; PBN[c * 4 + 1] = a1_;                      \
            PBN[c * 4 + 2] = b0_; PBN[c * 4 + 3] = b1_;                      \
        }                                                                    \
    } while (0)

// tile T: load V(T)->VFN, cluster {QK(T) w/ KU, PV(T-1) w/ VFP,PBP},
// prefetch K(T+2)->KU, softmax(T)->PBN.
#define ATTN_STEP(T, KU, VFP, VFN, PBP, PBN, DOPF)                           \
    do {                                                                     \
        _Pragma("unroll")                                                    \
        for (int mf = 0; mf < 2; ++mf)                                       \
            _Pragma("unroll")                                                \
            for (int c = 0; c < 4; ++c)                                      \
                VFN[mf * 4 + c] = *(const bf16x8*)(vbase + (T) * 4096 +      \
                                                   mf * 2048 + c * 512);     \
        f32x16 st0, st1;                                                     \
        _Pragma("unroll")                                                    \
        for (int i = 0; i < 16; ++i) { st0[i] = 0.f; st1[i] = 0.f; }         \
        __builtin_amdgcn_s_setprio(1);                                       \
        _Pragma("unroll")                                                    \
        for (int c = 0; c < 4; ++c) {                                        \
            st0 = MFMA32(KU[c], qf[c], st0);                                 \
            st1 = MFMA32(KU[4 + c], qf[c], st1);                             \
            union { u32 u[4]; bf16x8 v; } pv_;                               \
            pv_.u[0] = PBP[c * 4 + 0]; pv_.u[1] = PBP[c * 4 + 1];            \
            pv_.u[2] = PBP[c * 4 + 2]; pv_.u[3] = PBP[c * 4 + 3];            \
            oacc[0] = MFMA32(VFP[c], pv_.v, oacc[0]);                        \
            oacc[1] = MFMA32(VFP[4 + c], pv_.v, oacc[1]);                    \
        }                                                                    \
        __builtin_amdgcn_s_setprio(0);                                       \
        if (DOPF) {                                                          \
            const int ktp_ = ((T) + 2 < NT) ? (T) + 2 : NT - 1;              \
            _Pragma("unroll")                                                \
            for (int mf = 0; mf < 2; ++mf)                                   \
                _Pragma("unroll")                                            \
                for (int c = 0; c < 4; ++c)                                  \
                    KU[mf * 4 + c] = *(const bf16x8*)(kbase + ktp_ * 4096 +  \
                                                      mf * 2048 + c * 512);  \
        }                                                                    \
        ATTN_SMPACK(st0, st1, PBN);                                          \
    } while (0)

__global__ __launch_bounds__(256, 2) void attn_kernel(
    const bf16* __restrict__ q, const bf16* __restrict__ k,
    const bf16* __restrict__ vt, const float* __restrict__ wo,
    bf16* __restrict__ wot, bf16* __restrict__ o0) {
    __shared__ bf16 lds[4 * 2112];  // attn: epilogue transpose (wave-private)
                                    // tail blocks: 64x72 Wo transpose tile

    const int t = threadIdx.x;

    // ---- tail blocks (bid >= 512): Wo transpose (moved out of prep) ----
    if (blockIdx.x >= 512) {
        const int idx0 = blockIdx.x - 512;   // 0..255
        const int k0 = (idx0 >> 4) * 64, n0 = (idx0 & 15) * 64;
#pragma unroll
        for (int i = 0; i < 2; ++i) {
            int idx = i * 256 + t;
            int r = idx >> 3, c = (idx & 7) * 8;
            float4 a = *(const float4*)(wo + (k0 + r) * EE + n0 + c);
            float4 b = *(const float4*)(wo + (k0 + r) * EE + n0 + c + 4);
            bf16 tmp[8];
            tmp[0] = (bf16)a.x; tmp[1] = (bf16)a.y; tmp[2] = (bf16)a.z; tmp[3] = (bf16)a.w;
            tmp[4] = (bf16)b.x; tmp[5] = (bf16)b.y; tmp[6] = (bf16)b.z; tmp[7] = (bf16)b.w;
            *(uint4*)(lds + r * 72 + c) = *(uint4*)tmp;
        }
        __syncthreads();
#pragma unroll
        for (int i = 0; i < 2; ++i) {
            int idx = i * 256 + t;
            int n = idx >> 3, kc = (idx & 7) * 8;
            bf16 tmp[8];
#pragma unroll
            for (int j = 0; j < 8; ++j) tmp[j] = lds[(kc + j) * 72 + n];
            *(uint4*)(wot + (n0 + n) * EE + k0 + kc) = *(uint4*)tmp;
        }
        return;
    }

    const int w = t >> 6, lane = t & 63;
    const int q32 = lane & 31, h = lane >> 5;
    const int bh = blockIdx.x & 31;   // same-bh blocks share an XCD
    const int qb = blockIdx.x >> 5;   // 0..15 (128-row q tiles)
    const int qr0 = qb * 128 + w * 32;

    bf16x8 qf[4];
#pragma unroll
    for (int c = 0; c < 4; ++c)
        qf[c] = *(const bf16x8*)(q + (size_t)(bh * SS + qr0 + q32) * DD + c * 16 + h * 8);

    const bf16* kbase = k + (size_t)bh * 131072 + lane * 8;
    const bf16* vbase = vt + (size_t)bh * 131072 + lane * 8;

    f32x16 oacc[2];
#pragma unroll
    for (int i = 0; i < 16; ++i) { oacc[0][i] = 0.f; oacc[1][i] = 0.f; }
    float ls[4] = {0.f, 0.f, 0.f, 0.f};

    bf16x8 Ka[8], Kb[8], vfA[8], vfB[8];
    u32 pbA[16], pbB[16];

    // prologue: K(0)->Ka, K(1)->Kb, V(0)->vfA
#pragma unroll
    for (int mf = 0; mf < 2; ++mf)
#pragma unroll
        for (int c = 0; c < 4; ++c) {
            Ka[mf * 4 + c] = *(const bf16x8*)(kbase + mf * 2048 + c * 512);
            Kb[mf * 4 + c] = *(const bf16x8*)(kbase + 4096 + mf * 2048 + c * 512);
            vfA[mf * 4 + c] = *(const bf16x8*)(vbase + mf * 2048 + c * 512);
        }

    // QK(0) -> softmax -> pbA; then K(2)->Ka (Ka dead after QK(0))
    {
        f32x16 st0, st1;
#pragma unroll
        for (int i = 0; i < 16; ++i) { st0[i] = 0.f; st1[i] = 0.f; }
        __builtin_amdgcn_s_setprio(1);
#pragma unroll
        for (int c = 0; c < 4; ++c) {
            st0 = MFMA32(Ka[c], qf[c], st0);
            st1 = MFMA32(Ka[4 + c], qf[c], st1);
        }
        __builtin_amdgcn_s_setprio(0);
#pragma unroll
        for (int mf = 0; mf < 2; ++mf)
#pragma unroll
            for (int c = 0; c < 4; ++c)
                Ka[mf * 4 + c] = *(const bf16x8*)(kbase + 2 * 4096 + mf * 2048 + c * 512);
        ATTN_SMPACK(st0, st1, pbA);
    }

    // pipeline: t = 1..30 (15 x 2 steps), then t = 31
    for (int i = 0; i < 15; ++i) {
        ATTN_STEP(2 * i + 1, Kb, vfA, vfB, pbA, pbB, 1);
        ATTN_STEP(2 * i + 2, Ka, vfB, vfA, pbB, pbA, 1);
    }
    ATTN_STEP(31, Kb, vfA, vfB, pbA, pbB, 0);

    // drain: PV(31) from vfB, pbB
    __builtin_amdgcn_s_setprio(1);
#pragma unroll
    for (int c = 0; c < 4; ++c) {
        union { u32 u[4]; bf16x8 v; } pv_;
        pv_.u[0] = pbB[c * 4 + 0]; pv_.u[1] = pbB[c * 4 + 1];
        pv_.u[2] = pbB[c * 4 + 2]; pv_.u[3] = pbB[c * 4 + 3];
        oacc[0] = MFMA32(vfB[c], pv_.v, oacc[0]);
        oacc[1] = MFMA32(vfB[4 + c], pv_.v, oacc[1]);
    }
    __builtin_amdgcn_s_setprio(0);

    float lsum = (ls[0] + ls[1]) + (ls[2] + ls[3]);
    lsum += __shfl_xor(lsum, 32);
    const float inv = 1.f / lsum;

    bf16* ob = lds + w * 2112;  // 32 rows x stride 66, wave-private
#pragma unroll
    for (int mf = 0; mf < 2; ++mf)
#pragma unroll
        for (int rp = 0; rp < 8; ++rp) {
            const int d = 32 * mf + 2 * (rp & 1) + 8 * (rp >> 1) + 4 * h;
            *(u32*)(ob + q32 * 66 + d) =
                pkbf(oacc[mf][2 * rp] * inv, oacc[mf][2 * rp + 1] * inv);
        }
    __syncthreads();

    const int b = bh >> 4, head = bh & 15;
    const int half = lane & 1;
    const int r = lane >> 1;
#pragma unroll
    for (int i = 0; i < 4; ++i) {
        bf16x8 val = *(const bf16x8*)(ob + r * 66 + half * 32 + i * 8);
        *(bf16x8*)(o0 + (size_t)(b * SS + qr0 + r) * EE + head * DD +
                   half * 32 + i * 8) = val;
    }
}

// ---------------------------------------------------------------------------
// Single scratch layout, everything in d_ws (40 MiB).  d_out written exactly
// once, by gemm_o.
// ---------------------------------------------------------------------------
extern "C" void kernel_launch(void* const* d_in, const int* in_sizes, int n_in,
                              void* d_out, int out_size, void* d_ws, size_t ws_size,
                              hipStream_t stream) {
    const float* query = (const float*)d_in[0];
    const float* xi    = (const float*)d_in[1];
    const float* Wq = (const float*)d_in[2];  const float* bq = (const float*)d_in[3];
    const float* Wk = (const float*)d_in[4];  const float* bk = (const float*)d_in[5];
    const float* Wv = (const float*)d_in[6];  const float* bv = (const float*)d_in[7];
    const float* Wo = (const float*)d_in[8];  const float* bo = (const float*)d_in[9];
    const float* ew1 = (const float*)d_in[10]; const float* eb1 = (const float*)d_in[11];
    const float* lng = (const float*)d_in[12]; const float* lnb = (const float*)d_in[13];
    const float* ew2 = (const float*)d_in[14]; const float* eb2 = (const float*)d_in[15];
    const float* gate = (const float*)d_in[16];
    float* out = (float*)d_out;

    char* ws = (char*)d_ws;
    const size_t SZ = (size_t)MM * EE * sizeof(bf16);   // 8 MB
    const size_t WSZ = (size_t)EE * EE * sizeof(bf16);  // 2 MB per transposed weight

    bf16* queryc = (bf16*)(ws);            // dead after gemm_qkv
    bf16* p0     = (bf16*)(ws);            // attn output overlays queryc
    bf16* qws    = (bf16*)(ws + SZ);
    bf16* kws    = (bf16*)(ws + 2 * SZ);
    bf16* vtws   = (bf16*)(ws + 3 * SZ);
    bf16* wqT    = (bf16*)(ws + 4 * SZ);
    bf16* wkT    = (bf16*)(ws + 4 * SZ + WSZ);
    bf16* wvT    = (bf16*)(ws + 4 * SZ + 2 * WSZ);
    bf16* woT    = (bf16*)(ws + 4 * SZ + 3 * WSZ);
    float* adaptws = (float*)(ws + 4 * SZ + 4 * WSZ);

    // query conversion + Wq/Wk/Wv transpose + adapt (Wo transpose moved
    // to the attn dispatch tail)
    prep_kernel<<<2818, 256, 0, stream>>>(query, queryc, Wq, Wk, Wv,
                                          wqT, wkT, wvT,
                                          xi, ew1, eb1, lng, lnb, ew2, eb2, gate,
                                          adaptws);

    // combined QK (512) + V^T (256) = 768 blocks = 3/CU
    gemm_qkv<<<768, 256, 0, stream>>>(queryc, wqT, wvT, bq, bk, bv, adaptws,
                                      qws, vtws);

    // 512 attn blocks (32 bh x 16 q-tiles) + 256 Wo-transpose tail blocks
    attn_kernel<<<768, 256, 0, stream>>>(qws, kws, vtws, Wo, woT, p0);

    gemm_o<<<dim3(MM / 128, EE / 64), 256, 0, stream>>>(p0, woT, bo, out);
}